// Round 3
// baseline (569.940 us; speedup 1.0000x reference)
//
#include <hip/hip_runtime.h>
#include <hip/hip_bf16.h>

#define N_NODES 8192
#define HID 128
#define OUT_F 64
#define E_EDGES 262144
#define KTOT 192   // OUT_F + HID

typedef __bf16 bf16x8 __attribute__((ext_vector_type(8)));
typedef float  f32x4  __attribute__((ext_vector_type(4)));

__device__ __forceinline__ unsigned short f2bf(float f) {
    unsigned int u = __float_as_uint(f);
    u += 0x7fffu + ((u >> 16) & 1u);   // RNE
    return (unsigned short)(u >> 16);
}

// ================= CSR build (incoming edges per node) ======================
__global__ void count_k(const int* __restrict__ dst, int* __restrict__ cnt) {
    int e = blockIdx.x * 256 + threadIdx.x;
    if (e < E_EDGES) atomicAdd(&cnt[dst[e]], 1);
}

// 256 threads, each scans 32 nodes; writes off[0..8192] and cursor copy.
// Also zeroes stats[0..127] (saves a memset dispatch).
__global__ void scan_k(const int* __restrict__ cnt, int* __restrict__ off,
                       int* __restrict__ cursor, float* __restrict__ stats) {
    __shared__ int part[256];
    int tid = threadIdx.x;
    if (tid < 128) stats[tid] = 0.0f;
    int base = tid * 32;
    int local[32];
    int s = 0;
    #pragma unroll
    for (int j = 0; j < 32; ++j) { local[j] = s; s += cnt[base + j]; }
    part[tid] = s;
    __syncthreads();
    if (tid == 0) {
        int acc = 0;
        for (int i = 0; i < 256; ++i) { int t = part[i]; part[i] = acc; acc += t; }
    }
    __syncthreads();
    int p = part[tid];
    #pragma unroll
    for (int j = 0; j < 32; ++j) {
        int v = p + local[j];
        off[base + j] = v;
        cursor[base + j] = v;
    }
    if (tid == 255) off[N_NODES] = p + s;
}

__global__ void fill_k(const int* __restrict__ src, const int* __restrict__ dst,
                       int* __restrict__ cursor, int* __restrict__ eidx) {
    int e = blockIdx.x * 256 + threadIdx.x;
    if (e >= E_EDGES) return;
    int pos = atomicAdd(&cursor[dst[e]], 1);
    eidx[pos] = src[e];
}

// ======= pre_k: one pass over x computes BOTH input-side GEMMs + G x-part ===
//   h1 = x @ fc_w + fc_b        (64 cols)
//   y  = x @ w1                 (128 cols; bias applied post-gather)
//   G[:, 64:192] = x * SC (bf16)
__global__ __launch_bounds__(256)
void pre_k(const float* __restrict__ x,
           const float* __restrict__ fcw, const float* __restrict__ fcb,
           const float* __restrict__ w1,
           float* __restrict__ h1, float* __restrict__ y,
           unsigned short* __restrict__ G) {
    __shared__ float wS[64 * 192];   // 48 KB: K-slab [64][192] = [fc_w | w1]
    __shared__ float xs[16 * HID];   // 8 KB
    int tid = threadIdx.x;
    int rowbase = blockIdx.x * 16;

    for (int i = tid; i < 512; i += 256)
        *(float4*)&xs[i * 4] = *(const float4*)&x[(size_t)rowbase * HID + i * 4];

    int c = tid & 63, r0 = tid >> 6;   // rows r0, r0+4, r0+8, r0+12
    float acc[3][4] = {};

    for (int kh = 0; kh < 2; ++kh) {
        __syncthreads();   // covers xs staging (kh=0) and prev-phase reads
        for (int i = tid; i < 1024; i += 256) {
            int k = i >> 4, qd = i & 15;
            *(float4*)&wS[k * 192 + qd * 4] =
                *(const float4*)&fcw[(size_t)(kh * 64 + k) * 64 + qd * 4];
        }
        for (int i = tid; i < 2048; i += 256) {
            int k = i >> 5, qd = i & 31;
            *(float4*)&wS[k * 192 + 64 + qd * 4] =
                *(const float4*)&w1[(size_t)(kh * 64 + k) * 128 + qd * 4];
        }
        __syncthreads();
        #pragma unroll 4
        for (int k = 0; k < 64; ++k) {
            float wa = wS[k * 192 + c];
            float wb = wS[k * 192 + 64 + c];
            float wc = wS[k * 192 + 128 + c];
            #pragma unroll
            for (int g = 0; g < 4; ++g) {
                float xv = xs[(r0 + 4 * g) * HID + kh * 64 + k];  // broadcast
                acc[0][g] += xv * wa;
                acc[1][g] += xv * wb;
                acc[2][g] += xv * wc;
            }
        }
    }
    float b = fcb[c];
    #pragma unroll
    for (int g = 0; g < 4; ++g) {
        int r = rowbase + r0 + 4 * g;
        h1[(size_t)r * OUT_F + c]    = acc[0][g] + b;
        y[(size_t)r * HID + c]       = acc[1][g];
        y[(size_t)r * HID + 64 + c]  = acc[2][g];
    }
    const float SC = 0.70710678f;
    for (int i = tid; i < 2048; i += 256) {
        int r = i >> 7, cc = i & 127;
        G[(size_t)(rowbase + r) * KTOT + OUT_F + cc] = f2bf(xs[r * HID + cc] * SC);
    }
}

// == gather1 + mlp2 fused: z = relu(segsum(y)+w1_b) @ w2 (per-wave matvec) ===
__global__ __launch_bounds__(256)
void gather_mlp_k(const float* __restrict__ feat,
                  const int* __restrict__ eidx,
                  const int* __restrict__ off,
                  const float* __restrict__ bias,
                  const float* __restrict__ w2,
                  float* __restrict__ z) {
    __shared__ float wS[HID * 64];   // 32 KB: whole w2
    __shared__ float rowS[4][HID];   // per-wave h2 row
    int tid = threadIdx.x;
    int wid = tid >> 6, lane = tid & 63;

    // stage w2 (overlaps with the gather below; barrier before matvec)
    for (int i = tid; i < 2048; i += 256)
        *(float4*)&wS[i * 4] = *(const float4*)&w2[i * 4];

    int node = blockIdx.x * 4 + wid;
    int beg = off[node], end = off[node + 1];
    float2 a0{0,0}, a1{0,0}, a2{0,0}, a3{0,0}, a4{0,0}, a5{0,0}, a6{0,0}, a7{0,0};
    int j = beg;
    for (; j + 8 <= end; j += 8) {
        int s0 = eidx[j],     s1 = eidx[j + 1], s2 = eidx[j + 2], s3 = eidx[j + 3];
        int s4 = eidx[j + 4], s5 = eidx[j + 5], s6 = eidx[j + 6], s7 = eidx[j + 7];
        float2 v0 = *((const float2*)(feat + (size_t)s0 * HID) + lane);
        float2 v1 = *((const float2*)(feat + (size_t)s1 * HID) + lane);
        float2 v2 = *((const float2*)(feat + (size_t)s2 * HID) + lane);
        float2 v3 = *((const float2*)(feat + (size_t)s3 * HID) + lane);
        float2 v4 = *((const float2*)(feat + (size_t)s4 * HID) + lane);
        float2 v5 = *((const float2*)(feat + (size_t)s5 * HID) + lane);
        float2 v6 = *((const float2*)(feat + (size_t)s6 * HID) + lane);
        float2 v7 = *((const float2*)(feat + (size_t)s7 * HID) + lane);
        a0.x += v0.x; a0.y += v0.y;  a1.x += v1.x; a1.y += v1.y;
        a2.x += v2.x; a2.y += v2.y;  a3.x += v3.x; a3.y += v3.y;
        a4.x += v4.x; a4.y += v4.y;  a5.x += v5.x; a5.y += v5.y;
        a6.x += v6.x; a6.y += v6.y;  a7.x += v7.x; a7.y += v7.y;
    }
    for (; j < end; ++j) {
        int s0 = eidx[j];
        float2 v0 = *((const float2*)(feat + (size_t)s0 * HID) + lane);
        a0.x += v0.x; a0.y += v0.y;
    }
    float2 r;
    r.x = ((a0.x + a1.x) + (a2.x + a3.x)) + ((a4.x + a5.x) + (a6.x + a7.x));
    r.y = ((a0.y + a1.y) + (a2.y + a3.y)) + ((a4.y + a5.y) + (a6.y + a7.y));
    float2 bb = *((const float2*)bias + lane);
    rowS[wid][lane * 2]     = fmaxf(r.x + bb.x, 0.0f);
    rowS[wid][lane * 2 + 1] = fmaxf(r.y + bb.y, 0.0f);
    __syncthreads();   // wS staged + rowS visible

    float acc = 0.0f;
    #pragma unroll 8
    for (int k = 0; k < HID; ++k)
        acc += rowS[wid][k] * wS[k * 64 + lane];   // rowS: bcast, wS: conflict-free
    z[(size_t)node * OUT_F + lane] = acc;
}

// == gather2 + combine + G h-part + BN stats: 64-col gather =================
// h = (1-eps)*h1 + eps*(segsum(z) + w2_b); per-wave 4 nodes; block stats reduce
__global__ void gather_fuse_k(const float* __restrict__ z,
                              const int* __restrict__ eidx,
                              const int* __restrict__ off,
                              const float* __restrict__ h1,
                              const float* __restrict__ w2b,
                              const float* __restrict__ eps,
                              float* __restrict__ h,
                              unsigned short* __restrict__ G,
                              float* __restrict__ stats) {
    __shared__ float red[8][64];
    int tid = threadIdx.x;
    int wid = tid >> 6, lane = tid & 63;
    float s = 0.0f, q = 0.0f;
    float b = w2b[lane];
    const float SC = 0.70710678f;
    for (int t = 0; t < 4; ++t) {
        int node = blockIdx.x * 16 + wid * 4 + t;
        int beg = off[node], end = off[node + 1];
        float a0 = 0, a1 = 0, a2 = 0, a3 = 0, a4 = 0, a5 = 0, a6 = 0, a7 = 0;
        int j = beg;
        for (; j + 8 <= end; j += 8) {
            int s0 = eidx[j],     s1 = eidx[j + 1], s2 = eidx[j + 2], s3 = eidx[j + 3];
            int s4 = eidx[j + 4], s5 = eidx[j + 5], s6 = eidx[j + 6], s7 = eidx[j + 7];
            a0 += z[(size_t)s0 * OUT_F + lane];
            a1 += z[(size_t)s1 * OUT_F + lane];
            a2 += z[(size_t)s2 * OUT_F + lane];
            a3 += z[(size_t)s3 * OUT_F + lane];
            a4 += z[(size_t)s4 * OUT_F + lane];
            a5 += z[(size_t)s5 * OUT_F + lane];
            a6 += z[(size_t)s6 * OUT_F + lane];
            a7 += z[(size_t)s7 * OUT_F + lane];
        }
        for (; j < end; ++j)
            a0 += z[(size_t)eidx[j] * OUT_F + lane];
        float gs = ((a0 + a1) + (a2 + a3)) + ((a4 + a5) + (a6 + a7));
        float e = eps[node];
        float hv = (1.0f - e) * h1[(size_t)node * OUT_F + lane] + e * (gs + b);
        h[(size_t)node * OUT_F + lane] = hv;
        G[(size_t)node * KTOT + lane] = f2bf(hv * SC);
        s += hv;
        q += hv * hv;
    }
    red[wid][lane] = s;
    red[4 + wid][lane] = q;
    __syncthreads();
    if (tid < 64) {
        atomicAdd(&stats[tid],
                  (red[0][tid] + red[1][tid]) + (red[2][tid] + red[3][tid]));
    } else if (tid < 128) {
        int l = tid - 64;
        atomicAdd(&stats[64 + l],
                  (red[4][l] + red[5][l]) + (red[6][l] + red[7][l]));
    }
}

__global__ void bn_apply_k(const float* __restrict__ h,
                           const float* __restrict__ stats,
                           const float* __restrict__ gamma,
                           const float* __restrict__ beta,
                           float* __restrict__ outBN) {
    int idx = blockIdx.x * 256 + threadIdx.x;
    if (idx >= N_NODES * OUT_F) return;
    int c = idx & 63;
    const float inv_n = 1.0f / 8192.0f;
    float m = stats[c] * inv_n;
    float v = stats[64 + c] * inv_n - m * m;
    outBN[idx] = (h[idx] - m) * rsqrtf(v + 1e-5f) * gamma[c] + beta[c];
}

// ---------------- ret = G' @ G'^T (symmetric, LDS-free) ---------------------
// G (3 MB) is L2-resident; MFMA fragments load straight from global with
// perfect 64-B line utilization (lane-groups {l,l+16,l+32,l+48} cover one
// line per row per k-step). No LDS, no barriers; 2080 triangular blocks;
// nontemporal C stores keep the 268 MB ret stream from evicting G.
__global__ __launch_bounds__(256, 4)
void big_gemm_k(const unsigned short* __restrict__ G, float* __restrict__ C) {
    int bid = blockIdx.x;   // 0..2079 triangular
    int by = (int)((sqrtf(8.0f * bid + 1.0f) - 1.0f) * 0.5f);
    while ((by + 1) * (by + 2) / 2 <= bid) ++by;
    while (by * (by + 1) / 2 > bid) --by;
    int bx = bid - by * (by + 1) / 2;   // bx <= by

    int tid = threadIdx.x;
    int lane = tid & 63, wid = tid >> 6;
    int wm = wid >> 1, wn = wid & 1;
    int row0 = by * 128, col0 = bx * 128;

    const unsigned short* Abase =
        G + (size_t)(row0 + wm * 64 + (lane & 15)) * KTOT + (lane >> 4) * 8;
    const unsigned short* Bbase =
        G + (size_t)(col0 + wn * 64 + (lane & 15)) * KTOT + (lane >> 4) * 8;

    f32x4 acc[4][4] = {};

    #pragma unroll
    for (int kk = 0; kk < 6; ++kk) {    // K = 192 = 6 x 32
        bf16x8 af[4], bfr[4];
        #pragma unroll
        for (int t = 0; t < 4; ++t) {
            af[t]  = *(const bf16x8*)(Abase + (size_t)t * 16 * KTOT + kk * 32);
            bfr[t] = *(const bf16x8*)(Bbase + (size_t)t * 16 * KTOT + kk * 32);
        }
        #pragma unroll
        for (int tm = 0; tm < 4; ++tm)
            #pragma unroll
            for (int tn = 0; tn < 4; ++tn)
                acc[tm][tn] = __builtin_amdgcn_mfma_f32_16x16x32_bf16(
                    af[tm], bfr[tn], acc[tm][tn], 0, 0, 0);
    }

    // normal-orientation write: C/D layout col=lane&15, row=(lane>>4)*4+reg
    int crow = row0 + wm * 64 + (lane >> 4) * 4;
    int ccol = col0 + wn * 64 + (lane & 15);
    #pragma unroll
    for (int tm = 0; tm < 4; ++tm)
        #pragma unroll
        for (int tn = 0; tn < 4; ++tn)
            #pragma unroll
            for (int r = 0; r < 4; ++r)
                __builtin_nontemporal_store(acc[tm][tn][r],
                    &C[(size_t)(crow + tm * 16 + r) * N_NODES + (ccol + tn * 16)]);

    // mirrored tile (transpose): contiguous float4 along r
    if (bx != by) {
        int trow = col0 + wn * 64 + (lane & 15);      // mirrored row = orig col
        int tcol = row0 + wm * 64 + (lane >> 4) * 4;  // mirrored col base
        #pragma unroll
        for (int tm = 0; tm < 4; ++tm)
            #pragma unroll
            for (int tn = 0; tn < 4; ++tn) {
                f32x4 v = acc[tm][tn];
                __builtin_nontemporal_store(v,
                    (f32x4*)&C[(size_t)(trow + tn * 16) * N_NODES + tcol + tm * 16]);
            }
    }
}

extern "C" void kernel_launch(void* const* d_in, const int* in_sizes, int n_in,
                              void* d_out, int out_size, void* d_ws, size_t ws_size,
                              hipStream_t stream) {
    const float* x    = (const float*)d_in[0];
    // d_in[1] = adj (unused by reference)
    const int*   src  = (const int*)d_in[2];
    const int*   dst  = (const int*)d_in[3];
    const float* fcw  = (const float*)d_in[4];
    const float* fcb  = (const float*)d_in[5];
    const float* w1   = (const float*)d_in[6];
    const float* w1b  = (const float*)d_in[7];
    const float* w2   = (const float*)d_in[8];
    const float* w2b  = (const float*)d_in[9];
    const float* eps  = (const float*)d_in[10];
    const float* gamma= (const float*)d_in[11];
    const float* beta = (const float*)d_in[12];

    float* ws = (float*)d_ws;
    float* y     = ws;                        // 1048576 f : x @ w1
    float* h1    = ws + 1048576;              //  524288 f : x @ fc_w + fc_b
    float* z     = ws + 1572864;              //  524288 f : relu(gather(y)+b1) @ w2
    float* h     = ws + 2097152;              //  524288 f
    unsigned short* G = (unsigned short*)(ws + 2621440);   // 8192*192 bf16 = 786432 f
    float* stats = ws + 2621440 + 786432;     // 128 f  (G ends at 3407872)
    int*   cnt    = (int*)(ws + 3408000);     // 8192 i
    int*   off    = cnt + N_NODES;            // 8193 i
    int*   cursor = off + N_NODES + 1;        // 8192 i
    int*   eidx   = cursor + N_NODES;         // E i  (ends ~3694721 f, ~14.8 MB)

    float* ret   = (float*)d_out;                    // 8192*8192
    float* outBN = (float*)d_out + (size_t)N_NODES * N_NODES;  // 8192*64

    hipMemsetAsync(cnt, 0, N_NODES * sizeof(int), stream);

    dim3 blk(256);

    // --- CSR build (shared by both segment_sums); scan_k also zeroes stats ---
    count_k<<<E_EDGES / 256, blk, 0, stream>>>(dst, cnt);
    scan_k<<<1, blk, 0, stream>>>(cnt, off, cursor, stats);
    fill_k<<<E_EDGES / 256, blk, 0, stream>>>(src, dst, cursor, eidx);

    // y = x@w1, h1 = x@fc_w + b, G x-part  (one pass over x)
    pre_k<<<N_NODES / 16, blk, 0, stream>>>(x, fcw, fcb, w1, h1, y, G);
    // z = relu(segsum(y) + b1) @ w2   (gather1 + mlp2 fused)
    gather_mlp_k<<<N_NODES / 4, blk, 0, stream>>>(y, eidx, off, w1b, w2, z);
    // h = (1-eps)h1 + eps(segsum(z)+b2); G h-part; BN stats
    gather_fuse_k<<<N_NODES / 16, blk, 0, stream>>>(z, eidx, off, h1, w2b, eps,
                                                    h, G, stats);
    // BN apply
    bn_apply_k<<<(N_NODES * OUT_F) / 256, blk, 0, stream>>>(h, stats, gamma, beta, outBN);
    // ret = G'G'^T (symmetric, triangular grid)
    big_gemm_k<<<2080, blk, 0, stream>>>(G, ret);
}

// Round 4
// 541.968 us; speedup vs baseline: 1.0516x; 1.0516x over previous
//
#include <hip/hip_runtime.h>
#include <hip/hip_bf16.h>

#define N_NODES 8192
#define HID 128
#define OUT_F 64
#define E_EDGES 262144
#define KTOT 192   // OUT_F + HID
#define LDK 104    // padded LDS row stride for 96-element half-K panel

typedef __bf16 bf16x8 __attribute__((ext_vector_type(8)));
typedef float  f32x4  __attribute__((ext_vector_type(4)));

__device__ __forceinline__ unsigned short f2bf(float f) {
    unsigned int u = __float_as_uint(f);
    u += 0x7fffu + ((u >> 16) & 1u);   // RNE
    return (unsigned short)(u >> 16);
}

// ================= CSR build (incoming edges per node) ======================
__global__ void count_k(const int* __restrict__ dst, int* __restrict__ cnt) {
    int e = blockIdx.x * 256 + threadIdx.x;
    if (e < E_EDGES) atomicAdd(&cnt[dst[e]], 1);
}

// 256 threads, each scans 32 nodes; writes off[0..8192] and cursor copy.
// Also zeroes stats[0..127] (saves a memset dispatch).
__global__ void scan_k(const int* __restrict__ cnt, int* __restrict__ off,
                       int* __restrict__ cursor, float* __restrict__ stats) {
    __shared__ int part[256];
    int tid = threadIdx.x;
    if (tid < 128) stats[tid] = 0.0f;
    int base = tid * 32;
    int local[32];
    int s = 0;
    #pragma unroll
    for (int j = 0; j < 32; ++j) { local[j] = s; s += cnt[base + j]; }
    part[tid] = s;
    __syncthreads();
    if (tid == 0) {
        int acc = 0;
        for (int i = 0; i < 256; ++i) { int t = part[i]; part[i] = acc; acc += t; }
    }
    __syncthreads();
    int p = part[tid];
    #pragma unroll
    for (int j = 0; j < 32; ++j) {
        int v = p + local[j];
        off[base + j] = v;
        cursor[base + j] = v;
    }
    if (tid == 255) off[N_NODES] = p + s;
}

__global__ void fill_k(const int* __restrict__ src, const int* __restrict__ dst,
                       int* __restrict__ cursor, int* __restrict__ eidx) {
    int e = blockIdx.x * 256 + threadIdx.x;
    if (e >= E_EDGES) return;
    int pos = atomicAdd(&cursor[dst[e]], 1);
    eidx[pos] = src[e];
}

// ======= pre_k: one pass over x computes BOTH input-side GEMMs + G x-part ===
//   h1 = x @ fc_w + fc_b        (64 cols)
//   y  = x @ w1                 (128 cols; bias applied post-gather)
//   G[:, 64:192] = x * SC (bf16)
__global__ __launch_bounds__(256)
void pre_k(const float* __restrict__ x,
           const float* __restrict__ fcw, const float* __restrict__ fcb,
           const float* __restrict__ w1,
           float* __restrict__ h1, float* __restrict__ y,
           unsigned short* __restrict__ G) {
    __shared__ float wS[64 * 192];   // 48 KB: K-slab [64][192] = [fc_w | w1]
    __shared__ float xs[16 * HID];   // 8 KB
    int tid = threadIdx.x;
    int rowbase = blockIdx.x * 16;

    for (int i = tid; i < 512; i += 256)
        *(float4*)&xs[i * 4] = *(const float4*)&x[(size_t)rowbase * HID + i * 4];

    int c = tid & 63, r0 = tid >> 6;   // rows r0, r0+4, r0+8, r0+12
    float acc[3][4] = {};

    for (int kh = 0; kh < 2; ++kh) {
        __syncthreads();   // covers xs staging (kh=0) and prev-phase reads
        for (int i = tid; i < 1024; i += 256) {
            int k = i >> 4, qd = i & 15;
            *(float4*)&wS[k * 192 + qd * 4] =
                *(const float4*)&fcw[(size_t)(kh * 64 + k) * 64 + qd * 4];
        }
        for (int i = tid; i < 2048; i += 256) {
            int k = i >> 5, qd = i & 31;
            *(float4*)&wS[k * 192 + 64 + qd * 4] =
                *(const float4*)&w1[(size_t)(kh * 64 + k) * 128 + qd * 4];
        }
        __syncthreads();
        #pragma unroll 4
        for (int k = 0; k < 64; ++k) {
            float wa = wS[k * 192 + c];
            float wb = wS[k * 192 + 64 + c];
            float wc = wS[k * 192 + 128 + c];
            #pragma unroll
            for (int g = 0; g < 4; ++g) {
                float xv = xs[(r0 + 4 * g) * HID + kh * 64 + k];  // broadcast
                acc[0][g] += xv * wa;
                acc[1][g] += xv * wb;
                acc[2][g] += xv * wc;
            }
        }
    }
    float b = fcb[c];
    #pragma unroll
    for (int g = 0; g < 4; ++g) {
        int r = rowbase + r0 + 4 * g;
        h1[(size_t)r * OUT_F + c]    = acc[0][g] + b;
        y[(size_t)r * HID + c]       = acc[1][g];
        y[(size_t)r * HID + 64 + c]  = acc[2][g];
    }
    const float SC = 0.70710678f;
    for (int i = tid; i < 2048; i += 256) {
        int r = i >> 7, cc = i & 127;
        G[(size_t)(rowbase + r) * KTOT + OUT_F + cc] = f2bf(xs[r * HID + cc] * SC);
    }
}

// == gather1 + mlp2 fused: z = relu(segsum(y)+w1_b) @ w2 (per-wave matvec) ===
__global__ __launch_bounds__(256)
void gather_mlp_k(const float* __restrict__ feat,
                  const int* __restrict__ eidx,
                  const int* __restrict__ off,
                  const float* __restrict__ bias,
                  const float* __restrict__ w2,
                  float* __restrict__ z) {
    __shared__ float wS[HID * 64];   // 32 KB: whole w2
    __shared__ float rowS[4][HID];   // per-wave h2 row
    int tid = threadIdx.x;
    int wid = tid >> 6, lane = tid & 63;

    // stage w2 (overlaps with the gather below; barrier before matvec)
    for (int i = tid; i < 2048; i += 256)
        *(float4*)&wS[i * 4] = *(const float4*)&w2[i * 4];

    int node = blockIdx.x * 4 + wid;
    int beg = off[node], end = off[node + 1];
    float2 a0{0,0}, a1{0,0}, a2{0,0}, a3{0,0}, a4{0,0}, a5{0,0}, a6{0,0}, a7{0,0};
    int j = beg;
    for (; j + 8 <= end; j += 8) {
        int s0 = eidx[j],     s1 = eidx[j + 1], s2 = eidx[j + 2], s3 = eidx[j + 3];
        int s4 = eidx[j + 4], s5 = eidx[j + 5], s6 = eidx[j + 6], s7 = eidx[j + 7];
        float2 v0 = *((const float2*)(feat + (size_t)s0 * HID) + lane);
        float2 v1 = *((const float2*)(feat + (size_t)s1 * HID) + lane);
        float2 v2 = *((const float2*)(feat + (size_t)s2 * HID) + lane);
        float2 v3 = *((const float2*)(feat + (size_t)s3 * HID) + lane);
        float2 v4 = *((const float2*)(feat + (size_t)s4 * HID) + lane);
        float2 v5 = *((const float2*)(feat + (size_t)s5 * HID) + lane);
        float2 v6 = *((const float2*)(feat + (size_t)s6 * HID) + lane);
        float2 v7 = *((const float2*)(feat + (size_t)s7 * HID) + lane);
        a0.x += v0.x; a0.y += v0.y;  a1.x += v1.x; a1.y += v1.y;
        a2.x += v2.x; a2.y += v2.y;  a3.x += v3.x; a3.y += v3.y;
        a4.x += v4.x; a4.y += v4.y;  a5.x += v5.x; a5.y += v5.y;
        a6.x += v6.x; a6.y += v6.y;  a7.x += v7.x; a7.y += v7.y;
    }
    for (; j < end; ++j) {
        int s0 = eidx[j];
        float2 v0 = *((const float2*)(feat + (size_t)s0 * HID) + lane);
        a0.x += v0.x; a0.y += v0.y;
    }
    float2 r;
    r.x = ((a0.x + a1.x) + (a2.x + a3.x)) + ((a4.x + a5.x) + (a6.x + a7.x));
    r.y = ((a0.y + a1.y) + (a2.y + a3.y)) + ((a4.y + a5.y) + (a6.y + a7.y));
    float2 bb = *((const float2*)bias + lane);
    rowS[wid][lane * 2]     = fmaxf(r.x + bb.x, 0.0f);
    rowS[wid][lane * 2 + 1] = fmaxf(r.y + bb.y, 0.0f);
    __syncthreads();   // wS staged + rowS visible

    float acc = 0.0f;
    #pragma unroll 8
    for (int k = 0; k < HID; ++k)
        acc += rowS[wid][k] * wS[k * 64 + lane];   // rowS: bcast, wS: conflict-free
    z[(size_t)node * OUT_F + lane] = acc;
}

// == gather2 + combine + G h-part + BN stats: 64-col gather =================
// h = (1-eps)*h1 + eps*(segsum(z) + w2_b); per-wave 4 nodes; block stats reduce
__global__ void gather_fuse_k(const float* __restrict__ z,
                              const int* __restrict__ eidx,
                              const int* __restrict__ off,
                              const float* __restrict__ h1,
                              const float* __restrict__ w2b,
                              const float* __restrict__ eps,
                              float* __restrict__ h,
                              unsigned short* __restrict__ G,
                              float* __restrict__ stats) {
    __shared__ float red[8][64];
    int tid = threadIdx.x;
    int wid = tid >> 6, lane = tid & 63;
    float s = 0.0f, q = 0.0f;
    float b = w2b[lane];
    const float SC = 0.70710678f;
    for (int t = 0; t < 4; ++t) {
        int node = blockIdx.x * 16 + wid * 4 + t;
        int beg = off[node], end = off[node + 1];
        float a0 = 0, a1 = 0, a2 = 0, a3 = 0, a4 = 0, a5 = 0, a6 = 0, a7 = 0;
        int j = beg;
        for (; j + 8 <= end; j += 8) {
            int s0 = eidx[j],     s1 = eidx[j + 1], s2 = eidx[j + 2], s3 = eidx[j + 3];
            int s4 = eidx[j + 4], s5 = eidx[j + 5], s6 = eidx[j + 6], s7 = eidx[j + 7];
            a0 += z[(size_t)s0 * OUT_F + lane];
            a1 += z[(size_t)s1 * OUT_F + lane];
            a2 += z[(size_t)s2 * OUT_F + lane];
            a3 += z[(size_t)s3 * OUT_F + lane];
            a4 += z[(size_t)s4 * OUT_F + lane];
            a5 += z[(size_t)s5 * OUT_F + lane];
            a6 += z[(size_t)s6 * OUT_F + lane];
            a7 += z[(size_t)s7 * OUT_F + lane];
        }
        for (; j < end; ++j)
            a0 += z[(size_t)eidx[j] * OUT_F + lane];
        float gs = ((a0 + a1) + (a2 + a3)) + ((a4 + a5) + (a6 + a7));
        float e = eps[node];
        float hv = (1.0f - e) * h1[(size_t)node * OUT_F + lane] + e * (gs + b);
        h[(size_t)node * OUT_F + lane] = hv;
        G[(size_t)node * KTOT + lane] = f2bf(hv * SC);
        s += hv;
        q += hv * hv;
    }
    red[wid][lane] = s;
    red[4 + wid][lane] = q;
    __syncthreads();
    if (tid < 64) {
        atomicAdd(&stats[tid],
                  (red[0][tid] + red[1][tid]) + (red[2][tid] + red[3][tid]));
    } else if (tid < 128) {
        int l = tid - 64;
        atomicAdd(&stats[64 + l],
                  (red[4][l] + red[5][l]) + (red[6][l] + red[7][l]));
    }
}

// ---------------- ret = G' @ G'^T (symmetric, LDS-staged) -------------------
// LDS staging insulates MFMA operand loads from L2 pollution by the 268 MB
// ret store stream (lesson of R3). Triangular-linear grid: 2080 blocks, no
// null blocks. Nontemporal ret stores reduce L2 eviction of G panels.
// First 2048 blocks also apply BN (folds bn_apply_k's pass in).
__global__ __launch_bounds__(256, 2)
void big_gemm_k(const unsigned short* __restrict__ G, float* __restrict__ C,
                const float* __restrict__ h, const float* __restrict__ stats,
                const float* __restrict__ gamma, const float* __restrict__ beta,
                float* __restrict__ outBN) {
    int bid = blockIdx.x;   // 0..2079 triangular
    int tid = threadIdx.x;

    // ---- folded BN apply: 4 nodes per block for bid < 2048 ----
    if (bid < 2048) {
        int c = tid & 63, rr = tid >> 6;
        int node = bid * 4 + rr;
        const float inv_n = 1.0f / 8192.0f;
        float m = stats[c] * inv_n;
        float v = stats[64 + c] * inv_n - m * m;
        outBN[(size_t)node * OUT_F + c] =
            (h[(size_t)node * OUT_F + c] - m) * rsqrtf(v + 1e-5f) * gamma[c] + beta[c];
    }

    int by = (int)((sqrtf(8.0f * bid + 1.0f) - 1.0f) * 0.5f);
    while ((by + 1) * (by + 2) / 2 <= bid) ++by;
    while (by * (by + 1) / 2 > bid) --by;
    int bx = bid - by * (by + 1) / 2;   // bx <= by

    __shared__ unsigned short Ap[128 * LDK];   // 26 KB
    __shared__ unsigned short Bp[128 * LDK];   // 26 KB
    int lane = tid & 63, wid = tid >> 6;
    int wm = wid >> 1, wn = wid & 1;
    int row0 = by * 128, col0 = bx * 128;

    f32x4 acc[4][4] = {};

    #pragma unroll
    for (int kh = 0; kh < 2; ++kh) {
        if (kh) __syncthreads();   // protect prev-phase reads
        // stage 128 rows x 96 cols (12 uint4 chunks) of each panel
        for (int i = tid; i < 128 * 12; i += 256) {
            int r = i / 12, cc = i % 12;
            *(uint4*)(&Ap[r * LDK + cc * 8]) =
                *(const uint4*)(G + (size_t)(row0 + r) * KTOT + kh * 96 + cc * 8);
            *(uint4*)(&Bp[r * LDK + cc * 8]) =
                *(const uint4*)(G + (size_t)(col0 + r) * KTOT + kh * 96 + cc * 8);
        }
        __syncthreads();
        int rA = wm * 64 + (lane & 15);
        int rB = wn * 64 + (lane & 15);
        int klane = (lane >> 4) * 8;
        #pragma unroll
        for (int ks = 0; ks < 3; ++ks) {
            bf16x8 af[4], bfr[4];
            #pragma unroll
            for (int t = 0; t < 4; ++t) {
                af[t]  = *(const bf16x8*)(&Ap[(rA + t * 16) * LDK + ks * 32 + klane]);
                bfr[t] = *(const bf16x8*)(&Bp[(rB + t * 16) * LDK + ks * 32 + klane]);
            }
            #pragma unroll
            for (int tm = 0; tm < 4; ++tm)
                #pragma unroll
                for (int tn = 0; tn < 4; ++tn)
                    acc[tm][tn] = __builtin_amdgcn_mfma_f32_16x16x32_bf16(
                        af[tm], bfr[tn], acc[tm][tn], 0, 0, 0);
        }
    }

    // normal-orientation write: C/D layout col=lane&15, row=(lane>>4)*4+reg
    int crow = row0 + wm * 64 + (lane >> 4) * 4;
    int ccol = col0 + wn * 64 + (lane & 15);
    #pragma unroll
    for (int tm = 0; tm < 4; ++tm)
        #pragma unroll
        for (int tn = 0; tn < 4; ++tn)
            #pragma unroll
            for (int r = 0; r < 4; ++r)
                __builtin_nontemporal_store(acc[tm][tn][r],
                    &C[(size_t)(crow + tm * 16 + r) * N_NODES + (ccol + tn * 16)]);

    // mirrored tile (transpose): contiguous float4 along r
    if (bx != by) {
        int trow = col0 + wn * 64 + (lane & 15);      // mirrored row = orig col
        int tcol = row0 + wm * 64 + (lane >> 4) * 4;  // mirrored col base
        #pragma unroll
        for (int tm = 0; tm < 4; ++tm)
            #pragma unroll
            for (int tn = 0; tn < 4; ++tn) {
                f32x4 v = acc[tm][tn];
                __builtin_nontemporal_store(v,
                    (f32x4*)&C[(size_t)(trow + tn * 16) * N_NODES + tcol + tm * 16]);
            }
    }
}

extern "C" void kernel_launch(void* const* d_in, const int* in_sizes, int n_in,
                              void* d_out, int out_size, void* d_ws, size_t ws_size,
                              hipStream_t stream) {
    const float* x    = (const float*)d_in[0];
    // d_in[1] = adj (unused by reference)
    const int*   src  = (const int*)d_in[2];
    const int*   dst  = (const int*)d_in[3];
    const float* fcw  = (const float*)d_in[4];
    const float* fcb  = (const float*)d_in[5];
    const float* w1   = (const float*)d_in[6];
    const float* w1b  = (const float*)d_in[7];
    const float* w2   = (const float*)d_in[8];
    const float* w2b  = (const float*)d_in[9];
    const float* eps  = (const float*)d_in[10];
    const float* gamma= (const float*)d_in[11];
    const float* beta = (const float*)d_in[12];

    float* ws = (float*)d_ws;
    float* y     = ws;                        // 1048576 f : x @ w1
    float* h1    = ws + 1048576;              //  524288 f : x @ fc_w + fc_b
    float* z     = ws + 1572864;              //  524288 f : relu(gather(y)+b1) @ w2
    float* h     = ws + 2097152;              //  524288 f
    unsigned short* G = (unsigned short*)(ws + 2621440);   // 8192*192 bf16 = 786432 f
    float* stats = ws + 2621440 + 786432;     // 128 f  (G ends at 3407872)
    int*   cnt    = (int*)(ws + 3408000);     // 8192 i
    int*   off    = cnt + N_NODES;            // 8193 i
    int*   cursor = off + N_NODES + 1;        // 8192 i
    int*   eidx   = cursor + N_NODES;         // E i  (ends ~3694721 f, ~14.8 MB)

    float* ret   = (float*)d_out;                    // 8192*8192
    float* outBN = (float*)d_out + (size_t)N_NODES * N_NODES;  // 8192*64

    hipMemsetAsync(cnt, 0, N_NODES * sizeof(int), stream);

    dim3 blk(256);

    // --- CSR build (shared by both segment_sums); scan_k also zeroes stats ---
    count_k<<<E_EDGES / 256, blk, 0, stream>>>(dst, cnt);
    scan_k<<<1, blk, 0, stream>>>(cnt, off, cursor, stats);
    fill_k<<<E_EDGES / 256, blk, 0, stream>>>(src, dst, cursor, eidx);

    // y = x@w1, h1 = x@fc_w + b, G x-part  (one pass over x)
    pre_k<<<N_NODES / 16, blk, 0, stream>>>(x, fcw, fcb, w1, h1, y, G);
    // z = relu(segsum(y) + b1) @ w2   (gather1 + mlp2 fused)
    gather_mlp_k<<<N_NODES / 4, blk, 0, stream>>>(y, eidx, off, w1b, w2, z);
    // h = (1-eps)h1 + eps(segsum(z)+b2); G h-part; BN stats
    gather_fuse_k<<<N_NODES / 16, blk, 0, stream>>>(z, eidx, off, h1, w2b, eps,
                                                    h, G, stats);
    // ret = G'G'^T (symmetric, triangular grid) + folded BN apply
    big_gemm_k<<<2080, blk, 0, stream>>>(G, ret, h, stats, gamma, beta, outBN);
}

// Round 5
// 526.298 us; speedup vs baseline: 1.0829x; 1.0298x over previous
//
#include <hip/hip_runtime.h>
#include <hip/hip_bf16.h>

#define N_NODES 8192
#define HID 128
#define OUT_F 64
#define E_EDGES 262144
#define KTOT 192   // OUT_F + HID
#define LDK 104    // padded LDS row stride for 96-element half-K panel

typedef __bf16 bf16x8 __attribute__((ext_vector_type(8)));
typedef float  f32x4  __attribute__((ext_vector_type(4)));

__device__ __forceinline__ unsigned short f2bf(float f) {
    unsigned int u = __float_as_uint(f);
    u += 0x7fffu + ((u >> 16) & 1u);   // RNE
    return (unsigned short)(u >> 16);
}

// ================= CSR build (incoming edges per node) ======================
__global__ void count_k(const int* __restrict__ dst, int* __restrict__ cnt) {
    int e = blockIdx.x * 256 + threadIdx.x;
    if (e < E_EDGES) atomicAdd(&cnt[dst[e]], 1);
}

// 256 threads, each scans 32 nodes; writes off[0..8192] and cursor copy.
// Also zeroes stats[0..127] (saves a memset dispatch).
__global__ void scan_k(const int* __restrict__ cnt, int* __restrict__ off,
                       int* __restrict__ cursor, float* __restrict__ stats) {
    __shared__ int part[256];
    int tid = threadIdx.x;
    if (tid < 128) stats[tid] = 0.0f;
    int base = tid * 32;
    int local[32];
    int s = 0;
    #pragma unroll
    for (int j = 0; j < 32; ++j) { local[j] = s; s += cnt[base + j]; }
    part[tid] = s;
    __syncthreads();
    if (tid == 0) {
        int acc = 0;
        for (int i = 0; i < 256; ++i) { int t = part[i]; part[i] = acc; acc += t; }
    }
    __syncthreads();
    int p = part[tid];
    #pragma unroll
    for (int j = 0; j < 32; ++j) {
        int v = p + local[j];
        off[base + j] = v;
        cursor[base + j] = v;
    }
    if (tid == 255) off[N_NODES] = p + s;
}

__global__ void fill_k(const int* __restrict__ src, const int* __restrict__ dst,
                       int* __restrict__ cursor, int* __restrict__ eidx) {
    int e = blockIdx.x * 256 + threadIdx.x;
    if (e >= E_EDGES) return;
    int pos = atomicAdd(&cursor[dst[e]], 1);
    eidx[pos] = src[e];
}

// ======= pre_k: one pass over x computes BOTH input-side GEMMs + G x-part ===
//   h1 = x @ fc_w + fc_b        (64 cols)
//   y  = x @ w1                 (128 cols; bias applied post-gather)
//   G[:, 64:192] = x * SC (bf16)
__global__ __launch_bounds__(256)
void pre_k(const float* __restrict__ x,
           const float* __restrict__ fcw, const float* __restrict__ fcb,
           const float* __restrict__ w1,
           float* __restrict__ h1, float* __restrict__ y,
           unsigned short* __restrict__ G) {
    __shared__ float wS[64 * 192];   // 48 KB: K-slab [64][192] = [fc_w | w1]
    __shared__ float xs[16 * HID];   // 8 KB
    int tid = threadIdx.x;
    int rowbase = blockIdx.x * 16;

    for (int i = tid; i < 512; i += 256)
        *(float4*)&xs[i * 4] = *(const float4*)&x[(size_t)rowbase * HID + i * 4];

    int c = tid & 63, r0 = tid >> 6;   // rows r0, r0+4, r0+8, r0+12
    float acc[3][4] = {};

    for (int kh = 0; kh < 2; ++kh) {
        __syncthreads();   // covers xs staging (kh=0) and prev-phase reads
        for (int i = tid; i < 1024; i += 256) {
            int k = i >> 4, qd = i & 15;
            *(float4*)&wS[k * 192 + qd * 4] =
                *(const float4*)&fcw[(size_t)(kh * 64 + k) * 64 + qd * 4];
        }
        for (int i = tid; i < 2048; i += 256) {
            int k = i >> 5, qd = i & 31;
            *(float4*)&wS[k * 192 + 64 + qd * 4] =
                *(const float4*)&w1[(size_t)(kh * 64 + k) * 128 + qd * 4];
        }
        __syncthreads();
        #pragma unroll 4
        for (int k = 0; k < 64; ++k) {
            float wa = wS[k * 192 + c];
            float wb = wS[k * 192 + 64 + c];
            float wc = wS[k * 192 + 128 + c];
            #pragma unroll
            for (int g = 0; g < 4; ++g) {
                float xv = xs[(r0 + 4 * g) * HID + kh * 64 + k];  // broadcast
                acc[0][g] += xv * wa;
                acc[1][g] += xv * wb;
                acc[2][g] += xv * wc;
            }
        }
    }
    float b = fcb[c];
    #pragma unroll
    for (int g = 0; g < 4; ++g) {
        int r = rowbase + r0 + 4 * g;
        h1[(size_t)r * OUT_F + c]    = acc[0][g] + b;
        y[(size_t)r * HID + c]       = acc[1][g];
        y[(size_t)r * HID + 64 + c]  = acc[2][g];
    }
    const float SC = 0.70710678f;
    for (int i = tid; i < 2048; i += 256) {
        int r = i >> 7, cc = i & 127;
        G[(size_t)(rowbase + r) * KTOT + OUT_F + cc] = f2bf(xs[r * HID + cc] * SC);
    }
}

// == gather1 + mlp2 fused: z = relu(segsum(y)+w1_b) @ w2 (per-wave matvec) ===
__global__ __launch_bounds__(256)
void gather_mlp_k(const float* __restrict__ feat,
                  const int* __restrict__ eidx,
                  const int* __restrict__ off,
                  const float* __restrict__ bias,
                  const float* __restrict__ w2,
                  float* __restrict__ z) {
    __shared__ float wS[HID * 64];   // 32 KB: whole w2
    __shared__ float rowS[4][HID];   // per-wave h2 row
    int tid = threadIdx.x;
    int wid = tid >> 6, lane = tid & 63;

    // stage w2 (overlaps with the gather below; barrier before matvec)
    for (int i = tid; i < 2048; i += 256)
        *(float4*)&wS[i * 4] = *(const float4*)&w2[i * 4];

    int node = blockIdx.x * 4 + wid;
    int beg = off[node], end = off[node + 1];
    float2 a0{0,0}, a1{0,0}, a2{0,0}, a3{0,0}, a4{0,0}, a5{0,0}, a6{0,0}, a7{0,0};
    int j = beg;
    for (; j + 8 <= end; j += 8) {
        int s0 = eidx[j],     s1 = eidx[j + 1], s2 = eidx[j + 2], s3 = eidx[j + 3];
        int s4 = eidx[j + 4], s5 = eidx[j + 5], s6 = eidx[j + 6], s7 = eidx[j + 7];
        float2 v0 = *((const float2*)(feat + (size_t)s0 * HID) + lane);
        float2 v1 = *((const float2*)(feat + (size_t)s1 * HID) + lane);
        float2 v2 = *((const float2*)(feat + (size_t)s2 * HID) + lane);
        float2 v3 = *((const float2*)(feat + (size_t)s3 * HID) + lane);
        float2 v4 = *((const float2*)(feat + (size_t)s4 * HID) + lane);
        float2 v5 = *((const float2*)(feat + (size_t)s5 * HID) + lane);
        float2 v6 = *((const float2*)(feat + (size_t)s6 * HID) + lane);
        float2 v7 = *((const float2*)(feat + (size_t)s7 * HID) + lane);
        a0.x += v0.x; a0.y += v0.y;  a1.x += v1.x; a1.y += v1.y;
        a2.x += v2.x; a2.y += v2.y;  a3.x += v3.x; a3.y += v3.y;
        a4.x += v4.x; a4.y += v4.y;  a5.x += v5.x; a5.y += v5.y;
        a6.x += v6.x; a6.y += v6.y;  a7.x += v7.x; a7.y += v7.y;
    }
    for (; j < end; ++j) {
        int s0 = eidx[j];
        float2 v0 = *((const float2*)(feat + (size_t)s0 * HID) + lane);
        a0.x += v0.x; a0.y += v0.y;
    }
    float2 r;
    r.x = ((a0.x + a1.x) + (a2.x + a3.x)) + ((a4.x + a5.x) + (a6.x + a7.x));
    r.y = ((a0.y + a1.y) + (a2.y + a3.y)) + ((a4.y + a5.y) + (a6.y + a7.y));
    float2 bb = *((const float2*)bias + lane);
    rowS[wid][lane * 2]     = fmaxf(r.x + bb.x, 0.0f);
    rowS[wid][lane * 2 + 1] = fmaxf(r.y + bb.y, 0.0f);
    __syncthreads();   // wS staged + rowS visible

    float acc = 0.0f;
    #pragma unroll 8
    for (int k = 0; k < HID; ++k)
        acc += rowS[wid][k] * wS[k * 64 + lane];   // rowS: bcast, wS: conflict-free
    z[(size_t)node * OUT_F + lane] = acc;
}

// == gather2 + combine + G h-part + BN stats: 64-col gather =================
// h = (1-eps)*h1 + eps*(segsum(z) + w2_b); per-wave 4 nodes; block stats reduce
__global__ void gather_fuse_k(const float* __restrict__ z,
                              const int* __restrict__ eidx,
                              const int* __restrict__ off,
                              const float* __restrict__ h1,
                              const float* __restrict__ w2b,
                              const float* __restrict__ eps,
                              float* __restrict__ h,
                              unsigned short* __restrict__ G,
                              float* __restrict__ stats) {
    __shared__ float red[8][64];
    int tid = threadIdx.x;
    int wid = tid >> 6, lane = tid & 63;
    float s = 0.0f, q = 0.0f;
    float b = w2b[lane];
    const float SC = 0.70710678f;
    for (int t = 0; t < 4; ++t) {
        int node = blockIdx.x * 16 + wid * 4 + t;
        int beg = off[node], end = off[node + 1];
        float a0 = 0, a1 = 0, a2 = 0, a3 = 0, a4 = 0, a5 = 0, a6 = 0, a7 = 0;
        int j = beg;
        for (; j + 8 <= end; j += 8) {
            int s0 = eidx[j],     s1 = eidx[j + 1], s2 = eidx[j + 2], s3 = eidx[j + 3];
            int s4 = eidx[j + 4], s5 = eidx[j + 5], s6 = eidx[j + 6], s7 = eidx[j + 7];
            a0 += z[(size_t)s0 * OUT_F + lane];
            a1 += z[(size_t)s1 * OUT_F + lane];
            a2 += z[(size_t)s2 * OUT_F + lane];
            a3 += z[(size_t)s3 * OUT_F + lane];
            a4 += z[(size_t)s4 * OUT_F + lane];
            a5 += z[(size_t)s5 * OUT_F + lane];
            a6 += z[(size_t)s6 * OUT_F + lane];
            a7 += z[(size_t)s7 * OUT_F + lane];
        }
        for (; j < end; ++j)
            a0 += z[(size_t)eidx[j] * OUT_F + lane];
        float gs = ((a0 + a1) + (a2 + a3)) + ((a4 + a5) + (a6 + a7));
        float e = eps[node];
        float hv = (1.0f - e) * h1[(size_t)node * OUT_F + lane] + e * (gs + b);
        h[(size_t)node * OUT_F + lane] = hv;
        G[(size_t)node * KTOT + lane] = f2bf(hv * SC);
        s += hv;
        q += hv * hv;
    }
    red[wid][lane] = s;
    red[4 + wid][lane] = q;
    __syncthreads();
    if (tid < 64) {
        atomicAdd(&stats[tid],
                  (red[0][tid] + red[1][tid]) + (red[2][tid] + red[3][tid]));
    } else if (tid < 128) {
        int l = tid - 64;
        atomicAdd(&stats[64 + l],
                  (red[4][l] + red[5][l]) + (red[6][l] + red[7][l]));
    }
}

// ---------------- ret = G' @ G'^T (symmetric, LDS-staged) -------------------
// LDS staging insulates MFMA operand loads from L2 pollution by the 268 MB
// ret store stream (lesson of R3). Triangular-linear grid: 2080 blocks, no
// null blocks. PLAIN stores (lesson of R4: nt stores regressed ~13 µs —
// sub-line 64 B granules need L2 write-combining).
// First 2048 blocks also apply BN (folds bn_apply_k's pass in).
__global__ __launch_bounds__(256, 2)
void big_gemm_k(const unsigned short* __restrict__ G, float* __restrict__ C,
                const float* __restrict__ h, const float* __restrict__ stats,
                const float* __restrict__ gamma, const float* __restrict__ beta,
                float* __restrict__ outBN) {
    int bid = blockIdx.x;   // 0..2079 triangular
    int tid = threadIdx.x;

    // ---- folded BN apply: 4 nodes per block for bid < 2048 ----
    if (bid < 2048) {
        int c = tid & 63, rr = tid >> 6;
        int node = bid * 4 + rr;
        const float inv_n = 1.0f / 8192.0f;
        float m = stats[c] * inv_n;
        float v = stats[64 + c] * inv_n - m * m;
        outBN[(size_t)node * OUT_F + c] =
            (h[(size_t)node * OUT_F + c] - m) * rsqrtf(v + 1e-5f) * gamma[c] + beta[c];
    }

    int by = (int)((sqrtf(8.0f * bid + 1.0f) - 1.0f) * 0.5f);
    while ((by + 1) * (by + 2) / 2 <= bid) ++by;
    while (by * (by + 1) / 2 > bid) --by;
    int bx = bid - by * (by + 1) / 2;   // bx <= by

    __shared__ unsigned short Ap[128 * LDK];   // 26 KB
    __shared__ unsigned short Bp[128 * LDK];   // 26 KB
    int lane = tid & 63, wid = tid >> 6;
    int wm = wid >> 1, wn = wid & 1;
    int row0 = by * 128, col0 = bx * 128;

    f32x4 acc[4][4] = {};

    #pragma unroll
    for (int kh = 0; kh < 2; ++kh) {
        if (kh) __syncthreads();   // protect prev-phase reads
        // stage 128 rows x 96 cols (12 uint4 chunks) of each panel
        for (int i = tid; i < 128 * 12; i += 256) {
            int r = i / 12, cc = i % 12;
            *(uint4*)(&Ap[r * LDK + cc * 8]) =
                *(const uint4*)(G + (size_t)(row0 + r) * KTOT + kh * 96 + cc * 8);
            *(uint4*)(&Bp[r * LDK + cc * 8]) =
                *(const uint4*)(G + (size_t)(col0 + r) * KTOT + kh * 96 + cc * 8);
        }
        __syncthreads();
        int rA = wm * 64 + (lane & 15);
        int rB = wn * 64 + (lane & 15);
        int klane = (lane >> 4) * 8;
        #pragma unroll
        for (int ks = 0; ks < 3; ++ks) {
            bf16x8 af[4], bfr[4];
            #pragma unroll
            for (int t = 0; t < 4; ++t) {
                af[t]  = *(const bf16x8*)(&Ap[(rA + t * 16) * LDK + ks * 32 + klane]);
                bfr[t] = *(const bf16x8*)(&Bp[(rB + t * 16) * LDK + ks * 32 + klane]);
            }
            #pragma unroll
            for (int tm = 0; tm < 4; ++tm)
                #pragma unroll
                for (int tn = 0; tn < 4; ++tn)
                    acc[tm][tn] = __builtin_amdgcn_mfma_f32_16x16x32_bf16(
                        af[tm], bfr[tn], acc[tm][tn], 0, 0, 0);
        }
    }

    // normal-orientation write: C/D layout col=lane&15, row=(lane>>4)*4+reg
    int crow = row0 + wm * 64 + (lane >> 4) * 4;
    int ccol = col0 + wn * 64 + (lane & 15);
    #pragma unroll
    for (int tm = 0; tm < 4; ++tm)
        #pragma unroll
        for (int tn = 0; tn < 4; ++tn)
            #pragma unroll
            for (int r = 0; r < 4; ++r)
                C[(size_t)(crow + tm * 16 + r) * N_NODES + (ccol + tn * 16)] =
                    acc[tm][tn][r];

    // mirrored tile (transpose): contiguous float4 along r
    if (bx != by) {
        int trow = col0 + wn * 64 + (lane & 15);      // mirrored row = orig col
        int tcol = row0 + wm * 64 + (lane >> 4) * 4;  // mirrored col base
        #pragma unroll
        for (int tm = 0; tm < 4; ++tm)
            #pragma unroll
            for (int tn = 0; tn < 4; ++tn)
                *(f32x4*)&C[(size_t)(trow + tn * 16) * N_NODES + tcol + tm * 16] =
                    acc[tm][tn];
    }
}

extern "C" void kernel_launch(void* const* d_in, const int* in_sizes, int n_in,
                              void* d_out, int out_size, void* d_ws, size_t ws_size,
                              hipStream_t stream) {
    const float* x    = (const float*)d_in[0];
    // d_in[1] = adj (unused by reference)
    const int*   src  = (const int*)d_in[2];
    const int*   dst  = (const int*)d_in[3];
    const float* fcw  = (const float*)d_in[4];
    const float* fcb  = (const float*)d_in[5];
    const float* w1   = (const float*)d_in[6];
    const float* w1b  = (const float*)d_in[7];
    const float* w2   = (const float*)d_in[8];
    const float* w2b  = (const float*)d_in[9];
    const float* eps  = (const float*)d_in[10];
    const float* gamma= (const float*)d_in[11];
    const float* beta = (const float*)d_in[12];

    float* ws = (float*)d_ws;
    float* y     = ws;                        // 1048576 f : x @ w1
    float* h1    = ws + 1048576;              //  524288 f : x @ fc_w + fc_b
    float* z     = ws + 1572864;              //  524288 f : relu(gather(y)+b1) @ w2
    float* h     = ws + 2097152;              //  524288 f
    unsigned short* G = (unsigned short*)(ws + 2621440);   // 8192*192 bf16 = 786432 f
    float* stats = ws + 2621440 + 786432;     // 128 f  (G ends at 3407872)
    int*   cnt    = (int*)(ws + 3408000);     // 8192 i
    int*   off    = cnt + N_NODES;            // 8193 i
    int*   cursor = off + N_NODES + 1;        // 8192 i
    int*   eidx   = cursor + N_NODES;         // E i  (ends ~3694721 f, ~14.8 MB)

    float* ret   = (float*)d_out;                    // 8192*8192
    float* outBN = (float*)d_out + (size_t)N_NODES * N_NODES;  // 8192*64

    hipMemsetAsync(cnt, 0, N_NODES * sizeof(int), stream);

    dim3 blk(256);

    // --- CSR build (shared by both segment_sums); scan_k also zeroes stats ---
    count_k<<<E_EDGES / 256, blk, 0, stream>>>(dst, cnt);
    scan_k<<<1, blk, 0, stream>>>(cnt, off, cursor, stats);
    fill_k<<<E_EDGES / 256, blk, 0, stream>>>(src, dst, cursor, eidx);

    // y = x@w1, h1 = x@fc_w + b, G x-part  (one pass over x)
    pre_k<<<N_NODES / 16, blk, 0, stream>>>(x, fcw, fcb, w1, h1, y, G);
    // z = relu(segsum(y) + b1) @ w2   (gather1 + mlp2 fused)
    gather_mlp_k<<<N_NODES / 4, blk, 0, stream>>>(y, eidx, off, w1b, w2, z);
    // h = (1-eps)h1 + eps(segsum(z)+b2); G h-part; BN stats
    gather_fuse_k<<<N_NODES / 16, blk, 0, stream>>>(z, eidx, off, h1, w2b, eps,
                                                    h, G, stats);
    // ret = G'G'^T (symmetric, triangular grid) + folded BN apply
    big_gemm_k<<<2080, blk, 0, stream>>>(G, ret, h, stats, gamma, beta, outBN);
}